// Round 1
// baseline (457.769 us; speedup 1.0000x reference)
//
#include <hip/hip_runtime.h>

#define B_ 2
#define S_ 2048
#define D_ 512
#define H_ 8
#define DH_ 64

typedef __bf16 bf16_8 __attribute__((ext_vector_type(8)));
typedef float f32x4 __attribute__((ext_vector_type(4)));

// ---------------------------------------------------------------------------
// Kernel 1: QKV projection.  y = x @ W^T  (torch Linear), bf16 outputs.
// z=0: Q (scaled by 1/8), z=1: K, z=2: V stored transposed [B,H,DH,S].
// Tiles: M=64 (rows of [4096,512]), N=64 (one head), K-chunks of 64.
// ---------------------------------------------------------------------------
__global__ __launch_bounds__(256) void proj_qkv(
    const float* __restrict__ Xq, const float* __restrict__ Xk, const float* __restrict__ Xv,
    const float* __restrict__ Wq, const float* __restrict__ Wk, const float* __restrict__ Wv,
    __bf16* __restrict__ Qb, __bf16* __restrict__ Kb, __bf16* __restrict__ Vt)
{
    const int z = blockIdx.z;
    const float* X = (z == 0) ? Xq : (z == 1) ? Xk : Xv;
    const float* W = (z == 0) ? Wq : (z == 1) ? Wk : Wv;
    const int m0 = blockIdx.x * 64;   // 0..4095
    const int n0 = blockIdx.y * 64;   // 0..511

    __shared__ __bf16 Xs[64][72];
    __shared__ __bf16 Ws[64][72];

    const int t = threadIdx.x;
    const int w = t >> 6, lane = t & 63;
    const int quad = lane >> 4, mc = lane & 15;

    f32x4 acc[4] = {};

    for (int kc = 0; kc < 512; kc += 64) {
        __syncthreads();
        for (int i = 0; i < 4; ++i) {
            int e = t + i * 256;           // 0..1023 covers 64x64 in float4 groups
            int r = e >> 4, c4 = (e & 15) * 4;
            float4 xv = *reinterpret_cast<const float4*>(&X[(size_t)(m0 + r) * 512 + kc + c4]);
            __bf16* dx = &Xs[r][c4];
            dx[0] = (__bf16)xv.x; dx[1] = (__bf16)xv.y; dx[2] = (__bf16)xv.z; dx[3] = (__bf16)xv.w;
            float4 wv = *reinterpret_cast<const float4*>(&W[(size_t)(n0 + r) * 512 + kc + c4]);
            __bf16* dw = &Ws[r][c4];
            dw[0] = (__bf16)wv.x; dw[1] = (__bf16)wv.y; dw[2] = (__bf16)wv.z; dw[3] = (__bf16)wv.w;
        }
        __syncthreads();
        for (int ks = 0; ks < 64; ks += 32) {
            bf16_8 a = *reinterpret_cast<const bf16_8*>(&Xs[w * 16 + mc][ks + quad * 8]);
            for (int tt = 0; tt < 4; ++tt) {
                bf16_8 b = *reinterpret_cast<const bf16_8*>(&Ws[tt * 16 + mc][ks + quad * 8]);
                acc[tt] = __builtin_amdgcn_mfma_f32_16x16x32_bf16(a, b, acc[tt], 0, 0, 0);
            }
        }
    }
    __syncthreads();
    // Epilogue via LDS (reuse Xs) for coalesced bf16 stores.
    const float scale = (z == 0) ? 0.125f : 1.0f;   // DH^-0.5 folded into Q
    if (z < 2) {
        for (int tt = 0; tt < 4; ++tt)
            for (int r = 0; r < 4; ++r)
                Xs[w * 16 + quad * 4 + r][tt * 16 + mc] = (__bf16)(acc[tt][r] * scale);
    } else {
        for (int tt = 0; tt < 4; ++tt)
            for (int r = 0; r < 4; ++r)
                Xs[tt * 16 + mc][w * 16 + quad * 4 + r] = (__bf16)acc[tt][r];  // transposed tile [dh][s]
    }
    __syncthreads();
    if (z < 2) {
        __bf16* out = (z == 0) ? Qb : Kb;
        for (int i = 0; i < 2; ++i) {
            int e = t + i * 256;           // 0..511 covers 64x64 in 8-elem groups
            int r = e >> 3, c8 = (e & 7) * 8;
            *reinterpret_cast<uint4*>(&out[(size_t)(m0 + r) * 512 + n0 + c8]) =
                *reinterpret_cast<const uint4*>(&Xs[r][c8]);
        }
    } else {
        int b = m0 >> 11, s0 = m0 & 2047, h = n0 >> 6;
        for (int i = 0; i < 2; ++i) {
            int e = t + i * 256;
            int r = e >> 3, c8 = (e & 7) * 8;   // r = dh, c8 = s offset
            *reinterpret_cast<uint4*>(&Vt[(((size_t)(b * H_ + h)) * DH_ + r) * S_ + s0 + c8]) =
                *reinterpret_cast<const uint4*>(&Xs[r][c8]);
        }
    }
}

// ---------------------------------------------------------------------------
// Kernel 2: attention. One WG = (b,h) x 64 q-rows. Two passes over k-chunks:
// pass 1: online (m,l); pass 2: recompute scores (bitwise identical), write
// normalized attention (fp32), PV-accumulate context via LDS-staged P.
// ---------------------------------------------------------------------------
__global__ __launch_bounds__(256) void attn_kernel(
    const __bf16* __restrict__ Qb, const __bf16* __restrict__ Kb, const __bf16* __restrict__ Vt,
    __bf16* __restrict__ Ctx, float* __restrict__ attn_out)
{
    const int qt = blockIdx.x;        // 0..31
    const int bh = blockIdx.y;        // 0..15
    const int b = bh >> 3, h = bh & 7;
    const int q0 = qt * 64;

    __shared__ __bf16 Qs[64][72];
    __shared__ __bf16 Ks[64][72];
    __shared__ __bf16 Ps[64][72];
    __shared__ __bf16 Vs[64][72];     // [dh][k] (transposed chunk)

    const int t = threadIdx.x;
    const int w = t >> 6, lane = t & 63;
    const int quad = lane >> 4, mc = lane & 15;

    for (int i = 0; i < 2; ++i) {
        int e = t + i * 256;
        int r = e >> 3, c8 = (e & 7) * 8;
        *reinterpret_cast<uint4*>(&Qs[r][c8]) =
            *reinterpret_cast<const uint4*>(&Qb[((size_t)b * S_ + q0 + r) * D_ + h * DH_ + c8]);
    }
    __syncthreads();
    const bf16_8 aq0 = *reinterpret_cast<const bf16_8*>(&Qs[w * 16 + mc][quad * 8]);
    const bf16_8 aq1 = *reinterpret_cast<const bf16_8*>(&Qs[w * 16 + mc][32 + quad * 8]);

    float m[4], l[4];
    for (int r = 0; r < 4; ++r) { m[r] = -1e30f; l[r] = 0.f; }

    // ---- pass 1: statistics ----
    for (int kc = 0; kc < S_; kc += 64) {
        __syncthreads();
        for (int i = 0; i < 2; ++i) {
            int e = t + i * 256;
            int r = e >> 3, c8 = (e & 7) * 8;
            *reinterpret_cast<uint4*>(&Ks[r][c8]) =
                *reinterpret_cast<const uint4*>(&Kb[((size_t)b * S_ + kc + r) * D_ + h * DH_ + c8]);
        }
        __syncthreads();
        f32x4 s[4] = {};
        for (int tt = 0; tt < 4; ++tt) {
            bf16_8 b0 = *reinterpret_cast<const bf16_8*>(&Ks[tt * 16 + mc][quad * 8]);
            s[tt] = __builtin_amdgcn_mfma_f32_16x16x32_bf16(aq0, b0, s[tt], 0, 0, 0);
        }
        for (int tt = 0; tt < 4; ++tt) {
            bf16_8 b1 = *reinterpret_cast<const bf16_8*>(&Ks[tt * 16 + mc][32 + quad * 8]);
            s[tt] = __builtin_amdgcn_mfma_f32_16x16x32_bf16(aq1, b1, s[tt], 0, 0, 0);
        }
        for (int r = 0; r < 4; ++r) {
            float mx = fmaxf(fmaxf(s[0][r], s[1][r]), fmaxf(s[2][r], s[3][r]));
            for (int off = 1; off < 16; off <<= 1) mx = fmaxf(mx, __shfl_xor(mx, off));
            float mn = fmaxf(m[r], mx);
            float sum = __expf(s[0][r] - mn) + __expf(s[1][r] - mn) +
                        __expf(s[2][r] - mn) + __expf(s[3][r] - mn);
            for (int off = 1; off < 16; off <<= 1) sum += __shfl_xor(sum, off);
            l[r] = l[r] * __expf(m[r] - mn) + sum;
            m[r] = mn;
        }
    }
    float linv[4];
    for (int r = 0; r < 4; ++r) linv[r] = 1.f / l[r];

    // ---- pass 2: write attention + PV ----
    f32x4 o[4] = {};
    for (int kc = 0; kc < S_; kc += 64) {
        __syncthreads();
        for (int i = 0; i < 2; ++i) {
            int e = t + i * 256;
            int r = e >> 3, c8 = (e & 7) * 8;
            *reinterpret_cast<uint4*>(&Ks[r][c8]) =
                *reinterpret_cast<const uint4*>(&Kb[((size_t)b * S_ + kc + r) * D_ + h * DH_ + c8]);
            *reinterpret_cast<uint4*>(&Vs[r][c8]) =
                *reinterpret_cast<const uint4*>(&Vt[((size_t)bh * DH_ + r) * S_ + kc + c8]);
        }
        __syncthreads();
        f32x4 s[4] = {};
        for (int tt = 0; tt < 4; ++tt) {
            bf16_8 b0 = *reinterpret_cast<const bf16_8*>(&Ks[tt * 16 + mc][quad * 8]);
            s[tt] = __builtin_amdgcn_mfma_f32_16x16x32_bf16(aq0, b0, s[tt], 0, 0, 0);
        }
        for (int tt = 0; tt < 4; ++tt) {
            bf16_8 b1 = *reinterpret_cast<const bf16_8*>(&Ks[tt * 16 + mc][32 + quad * 8]);
            s[tt] = __builtin_amdgcn_mfma_f32_16x16x32_bf16(aq1, b1, s[tt], 0, 0, 0);
        }
        // normalized p -> Ps (wave-private rows; no barrier needed)
        for (int tt = 0; tt < 4; ++tt)
            for (int r = 0; r < 4; ++r) {
                float p = __expf(s[tt][r] - m[r]) * linv[r];
                Ps[w * 16 + quad * 4 + r][tt * 16 + mc] = (__bf16)p;
            }
        // attention store: wave w covers its own 16 rows, float4 per lane
        for (int i = 0; i < 4; ++i) {
            int r = w * 16 + i * 4 + quad;
            const __bf16* ps = &Ps[r][mc * 4];
            float4 pv;
            pv.x = (float)ps[0]; pv.y = (float)ps[1]; pv.z = (float)ps[2]; pv.w = (float)ps[3];
            *reinterpret_cast<float4*>(
                &attn_out[((size_t)bh * S_ + q0 + r) * S_ + kc + mc * 4]) = pv;
        }
        // PV: A = Ps (own rows), B = Vs[dh][k]
        for (int ks = 0; ks < 64; ks += 32) {
            bf16_8 ap = *reinterpret_cast<const bf16_8*>(&Ps[w * 16 + mc][ks + quad * 8]);
            for (int tt = 0; tt < 4; ++tt) {
                bf16_8 bv = *reinterpret_cast<const bf16_8*>(&Vs[tt * 16 + mc][ks + quad * 8]);
                o[tt] = __builtin_amdgcn_mfma_f32_16x16x32_bf16(ap, bv, o[tt], 0, 0, 0);
            }
        }
    }
    // context epilogue via LDS (reuse Qs)
    __syncthreads();
    for (int tt = 0; tt < 4; ++tt)
        for (int r = 0; r < 4; ++r)
            Qs[w * 16 + quad * 4 + r][tt * 16 + mc] = (__bf16)o[tt][r];
    __syncthreads();
    for (int i = 0; i < 2; ++i) {
        int e = t + i * 256;
        int r = e >> 3, c8 = (e & 7) * 8;
        *reinterpret_cast<uint4*>(&Ctx[((size_t)b * S_ + q0 + r) * D_ + h * DH_ + c8]) =
            *reinterpret_cast<const uint4*>(&Qs[r][c8]);
    }
}

// ---------------------------------------------------------------------------
// Kernel 3a: output projection + bias + residual -> fp32 ws
// ---------------------------------------------------------------------------
__global__ __launch_bounds__(256) void oproj(
    const __bf16* __restrict__ Ctx, const float* __restrict__ Wo,
    const float* __restrict__ bo, const float* __restrict__ resid,
    float* __restrict__ Y)
{
    const int m0 = blockIdx.x * 64;
    const int n0 = blockIdx.y * 64;

    __shared__ __bf16 As[64][72];
    __shared__ __bf16 Bs[64][72];

    const int t = threadIdx.x;
    const int w = t >> 6, lane = t & 63;
    const int quad = lane >> 4, mc = lane & 15;

    f32x4 acc[4] = {};
    for (int kc = 0; kc < 512; kc += 64) {
        __syncthreads();
        for (int i = 0; i < 2; ++i) {
            int e = t + i * 256;
            int r = e >> 3, c8 = (e & 7) * 8;
            *reinterpret_cast<uint4*>(&As[r][c8]) =
                *reinterpret_cast<const uint4*>(&Ctx[(size_t)(m0 + r) * 512 + kc + c8]);
        }
        for (int i = 0; i < 4; ++i) {
            int e = t + i * 256;
            int r = e >> 4, c4 = (e & 15) * 4;
            float4 wv = *reinterpret_cast<const float4*>(&Wo[(size_t)(n0 + r) * 512 + kc + c4]);
            __bf16* dw = &Bs[r][c4];
            dw[0] = (__bf16)wv.x; dw[1] = (__bf16)wv.y; dw[2] = (__bf16)wv.z; dw[3] = (__bf16)wv.w;
        }
        __syncthreads();
        for (int ks = 0; ks < 64; ks += 32) {
            bf16_8 a = *reinterpret_cast<const bf16_8*>(&As[w * 16 + mc][ks + quad * 8]);
            for (int tt = 0; tt < 4; ++tt) {
                bf16_8 b = *reinterpret_cast<const bf16_8*>(&Bs[tt * 16 + mc][ks + quad * 8]);
                acc[tt] = __builtin_amdgcn_mfma_f32_16x16x32_bf16(a, b, acc[tt], 0, 0, 0);
            }
        }
    }
    for (int tt = 0; tt < 4; ++tt) {
        int col = n0 + tt * 16 + mc;
        float bias = bo[col];
        for (int r = 0; r < 4; ++r) {
            int row = m0 + w * 16 + quad * 4 + r;
            Y[(size_t)row * 512 + col] = acc[tt][r] + bias + resid[(size_t)row * 512 + col];
        }
    }
}

// ---------------------------------------------------------------------------
// Kernel 3b: LayerNorm over last dim (512). One wave per row.
// ---------------------------------------------------------------------------
__global__ __launch_bounds__(256) void ln_kernel(
    const float* __restrict__ Y, const float* __restrict__ gamma,
    const float* __restrict__ beta, float* __restrict__ out)
{
    const int row = blockIdx.x * 4 + (threadIdx.x >> 6);
    const int lane = threadIdx.x & 63;
    const float* y = &Y[(size_t)row * 512];
    float4 v0 = *reinterpret_cast<const float4*>(&y[lane * 8]);
    float4 v1 = *reinterpret_cast<const float4*>(&y[lane * 8 + 4]);
    float sum = v0.x + v0.y + v0.z + v0.w + v1.x + v1.y + v1.z + v1.w;
    float sq = v0.x * v0.x + v0.y * v0.y + v0.z * v0.z + v0.w * v0.w +
               v1.x * v1.x + v1.y * v1.y + v1.z * v1.z + v1.w * v1.w;
    for (int off = 1; off < 64; off <<= 1) {
        sum += __shfl_xor(sum, off);
        sq  += __shfl_xor(sq, off);
    }
    const float mean = sum * (1.f / 512.f);
    const float var = sq * (1.f / 512.f) - mean * mean;
    const float rstd = rsqrtf(var + 1e-5f);
    float4 g0 = *reinterpret_cast<const float4*>(&gamma[lane * 8]);
    float4 g1 = *reinterpret_cast<const float4*>(&gamma[lane * 8 + 4]);
    float4 b0 = *reinterpret_cast<const float4*>(&beta[lane * 8]);
    float4 b1 = *reinterpret_cast<const float4*>(&beta[lane * 8 + 4]);
    float4 o0, o1;
    o0.x = (v0.x - mean) * rstd * g0.x + b0.x;
    o0.y = (v0.y - mean) * rstd * g0.y + b0.y;
    o0.z = (v0.z - mean) * rstd * g0.z + b0.z;
    o0.w = (v0.w - mean) * rstd * g0.w + b0.w;
    o1.x = (v1.x - mean) * rstd * g1.x + b1.x;
    o1.y = (v1.y - mean) * rstd * g1.y + b1.y;
    o1.z = (v1.z - mean) * rstd * g1.z + b1.z;
    o1.w = (v1.w - mean) * rstd * g1.w + b1.w;
    *reinterpret_cast<float4*>(&out[(size_t)row * 512 + lane * 8]) = o0;
    *reinterpret_cast<float4*>(&out[(size_t)row * 512 + lane * 8 + 4]) = o1;
}

// ---------------------------------------------------------------------------
extern "C" void kernel_launch(void* const* d_in, const int* in_sizes, int n_in,
                              void* d_out, int out_size, void* d_ws, size_t ws_size,
                              hipStream_t stream)
{
    const float* query = (const float*)d_in[0];
    const float* key   = (const float*)d_in[1];
    const float* value = (const float*)d_in[2];
    const float* Wq    = (const float*)d_in[3];
    const float* Wk    = (const float*)d_in[4];
    const float* Wv    = (const float*)d_in[5];
    const float* Wo    = (const float*)d_in[6];
    const float* bo    = (const float*)d_in[7];
    const float* gamma = (const float*)d_in[8];
    const float* beta  = (const float*)d_in[9];

    float* out = (float*)d_out;                       // [output | attention]
    float* attn_out = out + (size_t)B_ * S_ * D_;     // offset 2*2048*512

    char* ws = (char*)d_ws;
    __bf16* Qb  = (__bf16*)(ws);                      // 4 MB, [B,S,D] bf16, pre-scaled
    __bf16* Kb  = (__bf16*)(ws + (4u << 20));         // 4 MB, [B,S,D]
    __bf16* Vt  = (__bf16*)(ws + (8u << 20));         // 4 MB, [B,H,DH,S]
    __bf16* Ctx = (__bf16*)(ws + (12u << 20));        // 4 MB, [B,S,D]
    float*  Y   = (float*)(ws + (16u << 20));         // 8 MB fp32

    proj_qkv<<<dim3(64, 8, 3), 256, 0, stream>>>(query, key, value, Wq, Wk, Wv, Qb, Kb, Vt);
    attn_kernel<<<dim3(32, 16), 256, 0, stream>>>(Qb, Kb, Vt, Ctx, attn_out);
    oproj<<<dim3(64, 8), 256, 0, stream>>>(Ctx, Wo, bo, query, Y);
    ln_kernel<<<1024, 256, 0, stream>>>(Y, gamma, beta, out);
}